// Round 1
// baseline (22.573 us; speedup 1.0000x reference)
//
#include <hip/hip_runtime.h>
#include <hip/hip_bf16.h>

#define NFEAT    16
#define NMF      7
#define NCLASSES 10
#define NRULES   512
#define BATCH    16384

#define WAVES 8                 // waves per block = rule splits
#define RPW   (NRULES / WAVES)  // 64 rules per wave
#define BLOCK (WAVES * 64)      // 512 threads

static_assert(BATCH % 64 == 0, "batch must be multiple of 64");
static_assert(NRULES % WAVES == 0, "rules must split evenly");

__global__ __launch_bounds__(BLOCK) void nefclass_kernel(
    const float* __restrict__ x,        // (NFEAT, BATCH)
    const float* __restrict__ mf_abc,   // (NFEAT, NMF, 3)
    const int*   __restrict__ rcond,    // (NRULES, NFEAT)
    const int*   __restrict__ rcls,     // (NRULES,)
    float*       __restrict__ out)      // (BATCH, NCLASSES)
{
    __shared__ float mem[NFEAT * NMF][64];                 // 28672 B, lane-fastest -> conflict-free gathers
    __shared__ unsigned long long pack[NRULES];            //  4096 B, 16 x 4-bit conds per rule
    __shared__ int cls[NRULES];                            //  2048 B
    __shared__ float acc[WAVES][NCLASSES][64];             // 20480 B

    const int tid   = threadIdx.x;
    const int lane  = tid & 63;
    const int wave  = tid >> 6;
    const int sbase = blockIdx.x * 64;
    const int j     = sbase + lane;   // this lane's sample

    // ---- stage 1: memberships for 64 samples, (f,m) pairs split over waves ----
    for (int p = wave; p < NFEAT * NMF; p += WAVES) {
        const int f = p / NMF;
        const int m = p - f * NMF;
        const float a = mf_abc[(f * NMF + m) * 3 + 0];
        const float b = mf_abc[(f * NMF + m) * 3 + 1];
        const float c = mf_abc[(f * NMF + m) * 3 + 2];
        const float xv = x[f * BATCH + j];
        const float l = (xv - a) / (b - a);
        const float r = (c - xv) / (c - b);
        float v = fminf(l, r);
        v = fminf(fmaxf(v, 0.0f), 1.0f);
        mem[p][lane] = v;
    }

    // ---- stage 2: pack rule conditions (1 rule per thread) + classes ----
    {
        const int r = tid;  // BLOCK == NRULES == 512
        unsigned long long pk = 0ull;
        #pragma unroll
        for (int f = 0; f < NFEAT; ++f)
            pk |= (unsigned long long)(rcond[r * NFEAT + f] & 7) << (4 * f);
        pack[r] = pk;
        cls[r]  = rcls[r];
    }

    // ---- stage 3: zero per-wave class accumulators ----
    #pragma unroll
    for (int c = 0; c < NCLASSES; ++c) acc[wave][c][lane] = 0.0f;

    __syncthreads();

    // ---- stage 4: rule loop (each wave owns RPW rules) ----
    const int r0 = wave * RPW;
    for (int r = r0; r < r0 + RPW; ++r) {
        const unsigned long long pk = pack[r];   // wave-uniform broadcast

        float v[8];
        #pragma unroll
        for (int f = 0; f < 8; ++f) {
            const int m = (int)((pk >> (4 * f)) & 7ull);
            v[f] = mem[f * NMF + m][lane];
        }
        float fir = fminf(fminf(fminf(v[0], v[1]), fminf(v[2], v[3])),
                          fminf(fminf(v[4], v[5]), fminf(v[6], v[7])));

        // exact early exit: min can only decrease; if every lane is already 0,
        // the final firing is 0 for all lanes and contributes nothing.
        if (!__any(fir > 0.0f)) continue;

        #pragma unroll
        for (int f = 8; f < 16; ++f) {
            const int m = (int)((pk >> (4 * f)) & 7ull);
            v[f - 8] = mem[f * NMF + m][lane];
        }
        const float fir2 = fminf(fminf(fminf(v[0], v[1]), fminf(v[2], v[3])),
                                 fminf(fminf(v[4], v[5]), fminf(v[6], v[7])));
        fir = fminf(fir, fir2);

        if (__any(fir > 0.0f)) {
            const int c = cls[r];                // wave-uniform
            acc[wave][c][lane] += fir;
        }
    }

    __syncthreads();

    // ---- stage 5: deterministic cross-wave reduce + coalesced store ----
    // outputs for this block: 64 samples x 10 classes = 640 floats, row-major (sample, class)
    for (int o = tid; o < 64 * NCLASSES; o += BLOCK) {
        const int s = o / NCLASSES;
        const int c = o - s * NCLASSES;
        float vsum = 0.0f;
        #pragma unroll
        for (int w = 0; w < WAVES; ++w) vsum += acc[w][c][s];
        out[sbase * NCLASSES + o] = vsum;   // == out[(sbase+s)*NCLASSES + c]
    }
}

extern "C" void kernel_launch(void* const* d_in, const int* in_sizes, int n_in,
                              void* d_out, int out_size, void* d_ws, size_t ws_size,
                              hipStream_t stream)
{
    const float* x     = (const float*)d_in[0];
    const float* mf    = (const float*)d_in[1];
    const int*   rcond = (const int*)d_in[2];
    const int*   rcls  = (const int*)d_in[3];
    float*       out   = (float*)d_out;

    dim3 grid(BATCH / 64);
    dim3 block(BLOCK);
    nefclass_kernel<<<grid, block, 0, stream>>>(x, mf, rcond, rcls, out);
}

// Round 2
// 10.410 us; speedup vs baseline: 2.1683x; 2.1683x over previous
//
#include <hip/hip_runtime.h>
#include <hip/hip_bf16.h>

#define NFEAT    16
#define NMF      7
#define NCLASSES 10
#define NRULES   512
#define BATCH    16384

#define WAVES 8
#define BLOCK (WAVES * 64)   // 512 threads; 8 waves; 64 samples per block; lane=sample in stages 1/rare, lane=rule in stage 2

static_assert(BATCH % 64 == 0, "");
static_assert(NRULES == BLOCK, "one rule per thread in stage 2");

__global__ __launch_bounds__(BLOCK) void nefclass_kernel(
    const float* __restrict__ x,        // (NFEAT, BATCH)
    const float* __restrict__ mf_abc,   // (NFEAT, NMF, 3)
    const int*   __restrict__ rcond,    // (NRULES, NFEAT)
    const int*   __restrict__ rcls,     // (NRULES,)
    float*       __restrict__ out)      // (BATCH, NCLASSES)
{
    __shared__ float mem[NFEAT * NMF][64];            // 28672 B, lane(=sample)-fastest
    __shared__ unsigned long long lmask[NFEAT * NMF]; //   896 B, bit j = (mem[p][j] > 0)
    __shared__ float acc[WAVES][NCLASSES][64];        // 20480 B (rare path only)
    __shared__ int anyfire;

    const int tid   = threadIdx.x;
    const int lane  = tid & 63;
    const int wave  = tid >> 6;
    const int sbase = blockIdx.x * 64;

    if (tid == 0) anyfire = 0;

    // ---- stage 1: memberships + per-(f,m) sample masks. wave w owns features 2w, 2w+1 ----
    {
        const int f0 = wave * 2;
        #pragma unroll
        for (int ff = 0; ff < 2; ++ff) {
            const int f = f0 + ff;
            const float xv = x[f * BATCH + sbase + lane];
            #pragma unroll
            for (int m = 0; m < NMF; ++m) {
                const int p = f * NMF + m;
                const float a = mf_abc[p * 3 + 0];
                const float b = mf_abc[p * 3 + 1];
                const float c = mf_abc[p * 3 + 2];
                float v = fminf((xv - a) / (b - a), (c - xv) / (c - b));
                v = fminf(fmaxf(v, 0.0f), 1.0f);
                mem[p][lane] = v;
                const unsigned long long bm = __ballot(v > 0.0f);
                if (lane == 0) lmask[p] = bm;
            }
        }
    }
    __syncthreads();

    // ---- stage 2: lane = rule. AND the 16 selected lane-masks -> per-rule sample mask ----
    const int r0 = wave * 64;
    const int r  = r0 + lane;
    const int4* rc = (const int4*)(rcond + r * NFEAT);  // 64 B per rule, aligned
    const int4 c0 = rc[0], c1 = rc[1], c2 = rc[2], c3 = rc[3];

    unsigned long long rm = ~0ull;
    rm &= lmask[ 0 * NMF + c0.x];
    rm &= lmask[ 1 * NMF + c0.y];
    rm &= lmask[ 2 * NMF + c0.z];
    rm &= lmask[ 3 * NMF + c0.w];
    rm &= lmask[ 4 * NMF + c1.x];
    rm &= lmask[ 5 * NMF + c1.y];
    rm &= lmask[ 6 * NMF + c1.z];
    rm &= lmask[ 7 * NMF + c1.w];
    rm &= lmask[ 8 * NMF + c2.x];
    rm &= lmask[ 9 * NMF + c2.y];
    rm &= lmask[10 * NMF + c2.z];
    rm &= lmask[11 * NMF + c2.w];
    rm &= lmask[12 * NMF + c3.x];
    rm &= lmask[13 * NMF + c3.y];
    rm &= lmask[14 * NMF + c3.z];
    rm &= lmask[15 * NMF + c3.w];

    unsigned long long fired = __ballot(rm != 0ull);   // wave-uniform
    if (fired != 0ull && lane == 0) anyfire = 1;
    __syncthreads();

    if (anyfire == 0) {
        // every firing in this block is exactly 0 -> output is exactly zero
        #pragma unroll
        for (int o = tid; o < 64 * NCLASSES; o += BLOCK)
            out[sbase * NCLASSES + o] = 0.0f;
        return;
    }

    // ---- rare path: full evaluation for fired rules only (exact, deterministic order) ----
    #pragma unroll
    for (int c = 0; c < NCLASSES; ++c) acc[wave][c][lane] = 0.0f;
    __syncthreads();

    while (fired != 0ull) {                    // ascending rule index within wave
        const int b = __ffsll(fired) - 1;
        fired &= fired - 1;
        const int rr = r0 + b;
        float fir = 1.0f;                      // memberships <= 1, so identity for min
        #pragma unroll
        for (int f = 0; f < NFEAT; ++f) {
            const int m = rcond[rr * NFEAT + f];          // wave-uniform scalar load
            fir = fminf(fir, mem[f * NMF + m][lane]);     // broadcast row, lane=sample
        }
        const int c = rcls[rr];                // wave-uniform
        acc[wave][c][lane] += fir;
    }
    __syncthreads();

    // waves hold disjoint rule ranges; sum w=0..7 ascending == reference rule order
    for (int o = tid; o < 64 * NCLASSES; o += BLOCK) {
        const int s = o / NCLASSES;
        const int c = o - s * NCLASSES;
        float vsum = 0.0f;
        #pragma unroll
        for (int w = 0; w < WAVES; ++w) vsum += acc[w][c][s];
        out[sbase * NCLASSES + o] = vsum;
    }
}

extern "C" void kernel_launch(void* const* d_in, const int* in_sizes, int n_in,
                              void* d_out, int out_size, void* d_ws, size_t ws_size,
                              hipStream_t stream)
{
    const float* x     = (const float*)d_in[0];
    const float* mf    = (const float*)d_in[1];
    const int*   rcond = (const int*)d_in[2];
    const int*   rcls  = (const int*)d_in[3];
    float*       out   = (float*)d_out;

    nefclass_kernel<<<dim3(BATCH / 64), dim3(BLOCK), 0, stream>>>(x, mf, rcond, rcls, out);
}